// Round 4
// baseline (735.375 us; speedup 1.0000x reference)
//
#include <hip/hip_runtime.h>
#include <stdint.h>

#define CH 256
#define HWD 56
#define POS 3136
#define BATCH 32
#define PW 58            // padded row width (cols 0..57; col 0 and 57 are zero pad)

typedef unsigned long long u64;
typedef __attribute__((ext_vector_type(4))) int  i32x4;
typedef __attribute__((ext_vector_type(16))) int i32x16;
typedef __attribute__((ext_vector_type(8))) short short8;

#define GLL16(gsrc, ldst) \
    __builtin_amdgcn_global_load_lds((const __attribute__((address_space(1))) void*)(gsrc), \
                                     (__attribute__((address_space(3))) void*)(ldst), 16, 0, 0)

// ---- pack weights, fragment-ordered: Wb2[tap][c/16][o][c%16] i8 (+1/-1) ----
__global__ void pack_w_kernel(const float* __restrict__ W, char* __restrict__ Wb2){
    int idx = blockIdx.x*256 + threadIdx.x;   // (o*9+tap)*16 + cc
    if (idx >= 256*9*16) return;
    int cc = idx & 15;
    int ot = idx >> 4;
    int o = ot / 9, tap = ot % 9;
    char v16[16];
    #pragma unroll
    for (int j=0;j<16;j++){
        float v = W[(size_t)(o*256 + cc*16 + j)*9 + tap];
        v16[j] = (v >= 0.f) ? 1 : -1;
    }
    *(int4*)(Wb2 + ((size_t)(tap*16 + cc)*256 + o)*16) = *(int4*)v16;
}

// ---- pack input signs, channel-last padded: SXp[b][r' 58][w' 58][c 256] i8 ----
__global__ __launch_bounds__(256) void pack_x_kernel(const float* __restrict__ x, char* __restrict__ SXp){
    int blk = blockIdx.x;              // b*58 + r'
    int rp = blk % 58, b = blk / 58;
    char* rowbase = SXp + ((size_t)(b*58 + rp))*PW*256;
    int t = threadIdx.x;
    if (rp == 0 || rp == 57){          // zero pad rows
        int* ip = (int*)rowbase;
        for (int j = t; j < PW*256/4; j += 256) ip[j] = 0;
        return;
    }
    int h = rp - 1;
    __shared__ char lds[56][256];
    int wave = t >> 6, l = t & 63;
    // phase 1: read x coalesced along w, write LDS transposed (swizzled banks)
    for (int i = 0; i < 64; ++i){
        int c = wave*64 + i;
        if (l < 56){
            float v = x[((size_t)(b*256 + c))*POS + h*HWD + l];
            lds[l][c ^ ((l & 31) << 2)] = (v >= 0.f) ? (char)1 : (char)-1;
        }
    }
    __syncthreads();
    // phase 2: write channel-last rows (256B contiguous per position)
    for (int i = 0; i < 15; ++i){
        int p = wave + 4*i;
        if (p >= 58) break;
        int val = 0;
        if (p >= 1 && p <= 56){
            int w = p - 1;
            val = *(const int*)&lds[w][(4*l) ^ ((w & 31) << 2)];
        }
        *(int*)(rowbase + p*256 + 4*l) = val;
    }
}

// ---- conv: i8 implicit GEMM. Block = (b, 4 output rows) x all 256 o ----
// 8 waves = 2 M-groups(128 o) x 4 N-groups(1 output row each)
__global__ __launch_bounds__(512) void conv_kernel(
        const char* __restrict__ SXp, const char* __restrict__ Wb2,
        short* __restrict__ y16, int* __restrict__ sumI, u64* __restrict__ sumQ){
    extern __shared__ char smem[];
    char* BL = smem;                  // [16 kb][6 row][68 slot][16B]  = 104448
    char* WL = smem + 104448;         // 2 x [4 kb'][256 o][16B]       = 32768

    int blk = blockIdx.x;
    int b  = blk / 14;
    int h0 = (blk % 14) * 4;
    int t = threadIdx.x;
    int wave = t >> 6, l = t & 63;
    int gm = wave >> 2;        // 0..1  (o-half)
    int gn = wave & 3;         // 0..3  (output row)
    int half = l >> 5;
    int l31 = l & 31;

    // ---- stage B once: 96 chunks of 1KB (kb 0..15, row 0..5) ----
    {
        const char* src0 = SXp + ((size_t)(b*58 + h0))*PW*256;
        for (int q = wave; q < 96; q += 8){
            int kb = q / 6, row = q % 6;
            const char* g = src0 + (size_t)row*PW*256 + l*256 + kb*16;  // per-lane stride 256
            char* d = BL + ((kb*6 + row)*68 + 1)*16;
            GLL16(g, d);
        }
        if (t < 192){                  // zero guard slots (w' = -1 and w' = 64)
            int kr = t >> 1, s = (t & 1) ? 65 : 0;
            *(int4*)(BL + (kr*68 + s)*16) = make_int4(0,0,0,0);
        }
    }

    i32x16 zero16;
    #pragma unroll
    for (int r=0;r<16;r++) zero16[r] = 0;
    i32x16 acc[4][2];
    #pragma unroll
    for (int m=0;m<4;m++){ acc[m][0] = zero16; acc[m][1] = zero16; }

    // ---- K loop: 36 quarter-stages (tap 0..8 x kq 0..3), W double-buffered ----
    // prologue: stage quarter 0 into buf 0
    {
        for (int qq = wave; qq < 16; qq += 8){
            int kbp = qq >> 2, oc = qq & 3;
            const char* g = Wb2 + ((size_t)(0*16 + 0*4 + kbp)*256 + oc*64 + l)*16;
            GLL16(g, WL + (kbp*256 + oc*64)*16);
        }
    }
    #pragma unroll 1
    for (int q = 0; q < 36; ++q){
        __syncthreads();               // drains W-quarter q (and B on q==0)
        if (q + 1 < 36){               // issue prefetch of quarter q+1 AFTER barrier
            int tap1 = (q+1) >> 2, kq1 = (q+1) & 3;
            char* dbuf = WL + ((q+1) & 1)*16384;
            for (int qq = wave; qq < 16; qq += 8){
                int kbp = qq >> 2, oc = qq & 3;
                const char* g = Wb2 + ((size_t)(tap1*16 + kq1*4 + kbp)*256 + oc*64 + l)*16;
                GLL16(g, dbuf + (kbp*256 + oc*64)*16);
            }
        }
        int tap = q >> 2, kq = q & 3;
        int dh = tap/3 - 1, dw = tap%3 - 1;
        int rowsel = gn + dh + 1;      // 0..5
        const char* wbuf = WL + (q & 1)*16384;
        #pragma unroll
        for (int ks = 0; ks < 2; ++ks){
            i32x4 afr[4], bfr[2];
            #pragma unroll
            for (int m=0;m<4;m++)
                afr[m] = *(const i32x4*)(wbuf + ((2*ks + half)*256 + gm*128 + m*32 + l31)*16);
            #pragma unroll
            for (int nt=0;nt<2;nt++)
                bfr[nt] = *(const i32x4*)(BL + (((kq*4 + 2*ks + half)*6 + rowsel)*68
                                               + 1 + nt*32 + dw + l31)*16);
            #pragma unroll
            for (int m=0;m<4;m++){
                acc[m][0] = __builtin_amdgcn_mfma_i32_32x32x32_i8(afr[m], bfr[0], acc[m][0], 0,0,0);
                acc[m][1] = __builtin_amdgcn_mfma_i32_32x32x32_i8(afr[m], bfr[1], acc[m][1], 0,0,0);
            }
        }
    }

    // ---- epilogue: store y (valid cols only) + exact integer stats ----
    int hrow = h0 + gn;
    int v0ok = (l31 >= 1);             // w' = l31      in 1..31  -> w = l31-1
    int v1ok = (l31 <= 24);            // w' = 32+l31  <= 56      -> w = l31+31
    #pragma unroll
    for (int m=0;m<4;m++){
        #pragma unroll
        for (int reg=0; reg<16; ++reg){
            int o = gm*128 + m*32 + (reg&3) + 8*(reg>>2) + 4*half;
            int v0 = acc[m][0][reg];
            int v1 = acc[m][1][reg];
            size_t ybase = ((size_t)(b*CH + o)*HWD + hrow)*HWD;
            if (v0ok) y16[ybase + (l31 - 1)]  = (short)v0;
            if (v1ok) y16[ybase + (l31 + 31)] = (short)v1;
            int s = (v0ok ? v0 : 0) + (v1ok ? v1 : 0);
            int qsq = (v0ok ? v0*v0 : 0) + (v1ok ? v1*v1 : 0);
            #pragma unroll
            for (int off=1; off<32; off<<=1){
                s   += __shfl_xor(s, off);
                qsq += __shfl_xor(qsq, off);
            }
            if (l31 == 0){
                atomicAdd(&sumI[o], s);
                atomicAdd(&sumQ[o], (u64)(unsigned)qsq);
            }
        }
    }
}

// ---- BN coefficients from exact integer sums ----
__global__ void bn_prep_kernel(const int* __restrict__ sumI, const u64* __restrict__ sumQ,
                               const float* __restrict__ gamma, const float* __restrict__ beta,
                               float* __restrict__ invA, float* __restrict__ shiftA){
    int o = threadIdx.x;
    const double N = (double)(BATCH*POS);
    double mean = (double)sumI[o] / N;
    double msq  = (double)sumQ[o] / N;
    double var  = msq - mean*mean;
    double inv  = (double)gamma[o] / sqrt(var + 1e-5);
    invA[o]   = (float)inv;
    shiftA[o] = (float)((double)beta[o] - mean*inv);
}

// ---- apply: out = y*inv + shift + x ----
__global__ void apply_kernel(const short* __restrict__ y16, const float* __restrict__ x,
                             const float* __restrict__ invA, const float* __restrict__ shiftA,
                             float* __restrict__ out){
    int t = blockIdx.x*blockDim.x + threadIdx.x;
    const int total8 = BATCH*CH*POS/8;
    if (t >= total8) return;
    size_t i = (size_t)t*8;
    int c = (t / (POS/8)) & 255;
    short8 yv = *(const short8*)(y16 + i);
    float4 x0 = *(const float4*)(x + i);
    float4 x1 = *(const float4*)(x + i + 4);
    float iv = invA[c], sh = shiftA[c];
    float4 o0, o1;
    o0.x = fmaf((float)yv[0], iv, sh) + x0.x;
    o0.y = fmaf((float)yv[1], iv, sh) + x0.y;
    o0.z = fmaf((float)yv[2], iv, sh) + x0.z;
    o0.w = fmaf((float)yv[3], iv, sh) + x0.w;
    o1.x = fmaf((float)yv[4], iv, sh) + x1.x;
    o1.y = fmaf((float)yv[5], iv, sh) + x1.y;
    o1.z = fmaf((float)yv[6], iv, sh) + x1.z;
    o1.w = fmaf((float)yv[7], iv, sh) + x1.w;
    *(float4*)(out + i)     = o0;
    *(float4*)(out + i + 4) = o1;
}

extern "C" void kernel_launch(void* const* d_in, const int* in_sizes, int n_in,
                              void* d_out, int out_size, void* d_ws, size_t ws_size,
                              hipStream_t stream) {
    const float* x     = (const float*)d_in[0];
    const float* W     = (const float*)d_in[1];
    const float* gamma = (const float*)d_in[2];
    const float* beta  = (const float*)d_in[3];
    float* out = (float*)d_out;

    // ws layout: y16 (51,380,224) | sumI (1024) | sumQ (2048) | invA | shiftA
    char* ws = (char*)d_ws;
    short* y16   = (short*)ws;
    int*   sumI  = (int*)(ws + 51380224);
    u64*   sumQ  = (u64*)(ws + 51381248);
    float* invA  = (float*)(ws + 51383296);
    float* shiftA= (float*)(ws + 51384320);

    // d_out doubles as scratch for SXp (27.6MB) + Wb2 (0.59MB); both dead
    // before apply_kernel overwrites d_out with the final result.
    char* ob  = (char*)d_out;
    char* SXp = ob;                      // 32*58*58*256 = 27,557,888
    char* Wb2 = ob + 28000000;           // 589,824

    hipMemsetAsync(sumI, 0, 3072, stream);

    pack_w_kernel<<<144, 256, 0, stream>>>(W, Wb2);
    pack_x_kernel<<<BATCH*58, 256, 0, stream>>>(x, SXp);

    hipFuncSetAttribute(reinterpret_cast<const void*>(conv_kernel),
                        hipFuncAttributeMaxDynamicSharedMemorySize, 137216);
    conv_kernel<<<BATCH*14, 512, 137216, stream>>>(SXp, Wb2, y16, sumI, sumQ);

    bn_prep_kernel<<<1, 256, 0, stream>>>(sumI, sumQ, gamma, beta, invA, shiftA);
    apply_kernel<<<(BATCH*CH*POS/8 + 255)/256, 256, 0, stream>>>(y16, x, invA, shiftA, out);
}